// Round 15
// baseline (238.749 us; speedup 1.0000x reference)
//
#include <hip/hip_runtime.h>
#include <hip/hip_bf16.h>
#include <stdint.h>

// MHA fwd, B=4 T=2048 D=768 H=12 HD=64, fp32 io, NO mask, scale=1/8.
// R20: R19 base + out_gemm re-tiled 128x128 with split-K=2 (atomicAdd into
// memset-zeroed out; bias from kz==0 only). Budget audit put out at ~40us
// for 9.7 GFLOP -- 16 MFMA/barrier-pair (vs qkv's 32) at 64x128 was the
// mechanism. New shape: grid (64,12)=768=3/CU exact, 6 K-iters/block,
// qkv-identical staging economics. prep/qkv/attn byte-frozen from R16/R19.

#define HH   12
#define TT   2048
#define DIN  768
#define DOUT 768
#define HD   64
#define BB   4
#define MTOT (BB*TT)      // 8192
#define NQKV (3*DOUT)     // 2304
#define QSCALE 0.1803368801111832f   // 0.125 * log2(e)

typedef float  float4v  __attribute__((ext_vector_type(4)));
typedef float  float16v __attribute__((ext_vector_type(16)));
typedef __bf16 bf16x8   __attribute__((ext_vector_type(8)));
typedef short  short8v  __attribute__((ext_vector_type(8)));

#define AS1 __attribute__((address_space(1)))
#define AS3 __attribute__((address_space(3)))

static __device__ __forceinline__ void gload_lds16(const void* g, void* l) {
    __builtin_amdgcn_global_load_lds((AS1 void*)g, (AS3 void*)l, 16, 0, 0);
}

static __device__ __forceinline__ short f2bf(float f) {
    __bf16 h = (__bf16)f;
    return __builtin_bit_cast(short, h);
}

// ---- Prep: weight transpose tiles only (x-cast fused into qkv) ----
__global__ __launch_bounds__(256) void prep_kernel(const float* __restrict__ Wq,
                                                   const float* __restrict__ Wk,
                                                   const float* __restrict__ Wv,
                                                   const float* __restrict__ Wo,
                                                   short* __restrict__ Wqkvt,
                                                   short* __restrict__ Wot) {
    __shared__ short tile[32 * 33];
    const int bz = blockIdx.z;
    const int bx = blockIdx.x, by = blockIdx.y;
    const float* W = (bz == 0) ? Wq : (bz == 1) ? Wk : (bz == 2) ? Wv : Wo;
    const int tx = threadIdx.x & 31, ty = threadIdx.x >> 5;
    for (int i = 0; i < 4; i++) {
        int k = by * 32 + ty + i * 8;
        tile[(ty + i * 8) * 33 + tx] = f2bf(W[(size_t)k * DOUT + bx * 32 + tx]);
    }
    __syncthreads();
    for (int i = 0; i < 4; i++) {
        int n = bx * 32 + ty + i * 8;
        int k = by * 32 + tx;
        short v = tile[tx * 33 + ty + i * 8];
        if (bz < 3) Wqkvt[(size_t)(bz * DOUT + n) * DIN + k] = v;
        else        Wot[(size_t)n * DOUT + k] = v;
    }
}

// ---- QKV GEMM (R16): C[8192][2304] = x(cast) @ Wqkvt^T, BK=64, M-fast. ----
__global__ __launch_bounds__(256) void qkv_gemm_kernel(const float* __restrict__ x,
                                                       const short* __restrict__ Wt,
                                                       short* __restrict__ Qb,
                                                       short* __restrict__ Kb,
                                                       short* __restrict__ Vt) {
    __shared__ __align__(16) short lds[16384];   // GEMM: A|B 32KB; epilogue: 32KB tile
    short* ldsA = lds;           // 128 x 64
    short* ldsB = lds + 8192;    // 128 x 64
    const int t = threadIdx.x;
    const int w = t >> 6, lane = t & 63;
    const int quad = lane >> 4, l15 = lane & 15;
    const int m0 = blockIdx.x * 128, n0 = blockIdx.y * 128;
    const int wm = (w >> 1) * 64, wn = (w & 1) * 64;

    float4v acc[4][4];
    for (int i = 0; i < 4; i++)
        for (int j = 0; j < 4; j++)
            acc[i][j] = (float4v)0.0f;

    const int rA = t >> 3;                               // 0..31
    const int cS = ((t & 7) ^ ((t >> 3) & 7)) * 8;       // source col-granule * 8
    const float* xA0 = x + (size_t)(m0 + rA) * DIN + cS;
    const short* gB0 = Wt + (size_t)(n0 + rA) * DIN + cS;

    for (int k0 = 0; k0 < DIN; k0 += 64) {
        // B first: fire-and-forget DMA while A reg-stages.
#pragma unroll
        for (int g = 0; g < 4; g++)
            gload_lds16(gB0 + (size_t)g * 32 * DIN + k0, &ldsB[(g * 256 + t) * 8]);
#pragma unroll
        for (int g = 0; g < 4; g++) {
            const float* src = xA0 + (size_t)g * 32 * DIN + k0;
            float4 lo = *(const float4*)src;
            float4 hi = *(const float4*)(src + 4);
            short8v s;
            s[0] = f2bf(lo.x); s[1] = f2bf(lo.y); s[2] = f2bf(lo.z); s[3] = f2bf(lo.w);
            s[4] = f2bf(hi.x); s[5] = f2bf(hi.y); s[6] = f2bf(hi.z); s[7] = f2bf(hi.w);
            *(short8v*)&ldsA[(g * 256 + t) * 8] = s;
        }
        __syncthreads();
#pragma unroll
        for (int kk = 0; kk < 2; kk++) {
            bf16x8 af[4], bfr[4];
            const int pos = ((kk * 4 + quad) ^ (l15 & 7)) * 8;
            for (int i = 0; i < 4; i++) af[i]  = *(const bf16x8*)&ldsA[(wm + i * 16 + l15) * 64 + pos];
            for (int j = 0; j < 4; j++) bfr[j] = *(const bf16x8*)&ldsB[(wn + j * 16 + l15) * 64 + pos];
            for (int i = 0; i < 4; i++)
                for (int j = 0; j < 4; j++)
                    acc[i][j] = __builtin_amdgcn_mfma_f32_16x16x32_bf16(af[i], bfr[j], acc[i][j], 0, 0, 0);
        }
        __syncthreads();
    }

    const int which = n0 / DOUT;
    if (which < 2) {
        // Q/K epilogue: single-pass 128x128 LDS tile, 1 barrier, b128 stores.
        short* ldsT = lds;   // 128 x 128 shorts = 32 KB
        const float sc = (which == 0) ? QSCALE : 1.0f;
        short* dst = (which == 0) ? Qb : Kb;
        const int n0sec = n0 - which * DOUT;
        for (int i = 0; i < 4; i++)
            for (int j = 0; j < 4; j++) {
                int col = wn + j * 16 + l15;
                int cx = col >> 3, co = col & 7;
                for (int r = 0; r < 4; r++) {
                    int row = wm + i * 16 + quad * 4 + r;
                    ldsT[row * 128 + ((cx ^ (row & 7)) * 8 + co)] = f2bf(acc[i][j][r] * sc);
                }
            }
        __syncthreads();
        for (int p = 0; p < 8; p++) {
            int row = p * 16 + (t >> 4);
            int cL = t & 15;
            short8v v = *(const short8v*)&ldsT[row * 128 + ((cL ^ (row & 7)) * 8)];
            int mg = m0 + row;
            int b2 = mg >> 11, tq = mg & 2047;
            int colg = n0sec + cL * 8;
            int hh = colg >> 6, d = colg & 63;
            *(short8v*)&dst[((size_t)((b2 * HH + hh) * TT + tq) << 6) + d] = v;
        }
    } else {
        // V epilogue: single-pass transpose 128(d) x 128(t) LDS tile, b128 stores.
        short* ldsT = lds;   // 128 x 128 shorts = 32 KB
        const int n0r = n0 - 2 * DOUT;
        const int b = m0 >> 11, tq0 = m0 & 2047;
        for (int i = 0; i < 4; i++)
            for (int j = 0; j < 4; j++)
                for (int r = 0; r < 4; r++) {
                    int nl = wn + j * 16 + l15;            // d-direction 0..127
                    int ml = wm + i * 16 + quad * 4 + r;   // t-direction 0..127
                    int c = ml >> 3, o = ml & 7;
                    ldsT[nl * 128 + ((c ^ (nl & 7)) * 8 + o)] = f2bf(acc[i][j][r]);
                }
        __syncthreads();
        for (int p = 0; p < 8; p++) {
            int nrow = p * 16 + (t >> 4);
            int cc = t & 15;
            short8v v = *(const short8v*)&ldsT[nrow * 128 + ((cc ^ (nrow & 7)) * 8)];
            int colg = n0r + nrow;
            int hh = colg >> 6, d = colg & 63;
            *(short8v*)&Vt[(size_t)((b * HH + hh) * HD + d) * TT + tq0 + cc * 8] = v;
        }
    }
}

// ---- Flash attention (R12/R9, banked): kt-interleave + T5 setprio ----
__global__ __launch_bounds__(256, 3) void attn_kernel(const short* __restrict__ Qb,
                                                      const short* __restrict__ Kb,
                                                      const short* __restrict__ Vt,
                                                      short* __restrict__ Ctx) {
    __shared__ __align__(16) short ldsK[2][64 * 64];
    __shared__ __align__(16) short ldsV[2][64 * 64];
    const int t = threadIdx.x;
    const int w = t >> 6, lane = t & 63;
    const int half = lane >> 5, m = lane & 31;
    const int bh = blockIdx.x;
    const int b = bh / HH, h = bh - b * HH;
    const int q0 = blockIdx.y * 128 + w * 32;

    const short* Qbase = Qb + (size_t)bh * TT * HD;
    const short* Kbase = Kb + (size_t)bh * TT * HD;
    const short* Vbase = Vt + (size_t)bh * HD * TT;

    bf16x8 qf[4];
#pragma unroll
    for (int s = 0; s < 4; s++)
        qf[s] = *(const bf16x8*)&Qbase[(q0 + m) * HD + s * 16 + half * 8];

    int kOff[2], vOff[2];
    {
        int r5 = t >> 3;
        int pi = ((r5 >> 3) & 1) * 16 + ((r5 >> 2) & 1) * 8 + ((r5 >> 4) & 1) * 4 + (r5 & 3);
#pragma unroll
        for (int g = 0; g < 2; g++) {
            kOff[g] = (g * 32 + pi) * 64 + (((t & 7) ^ (r5 & 7)) * 8);
            int vrow = g * 32 + r5;
            vOff[g] = vrow * TT + (((t & 7) ^ (vrow & 7)) * 8);
        }
    }

    auto stage = [&](int buf, int u0) {
#pragma unroll
        for (int g = 0; g < 2; g++)
            gload_lds16(Kbase + (size_t)u0 * 64 + kOff[g], &ldsK[buf][(g * 256 + t) * 8]);
#pragma unroll
        for (int g = 0; g < 2; g++)
            gload_lds16(Vbase + (size_t)u0 + vOff[g], &ldsV[buf][(g * 256 + t) * 8]);
    };

    float16v accO[2];
    accO[0] = (float16v)0.0f;
    accO[1] = (float16v)0.0f;
    float lsum = 0.0f;

    stage(0, 0);

    for (int it = 0; it < TT / 64; ++it) {
        __syncthreads();
        const int buf = it & 1;
        if (it + 1 < TT / 64) stage(buf ^ 1, (it + 1) * 64);
        const short* K_ = &ldsK[buf][0];
        const short* V_ = &ldsV[buf][0];

        // ---- QK for both kt halves: two independent accumulation chains ----
        float16v st0 = (float16v)0.0f;
        float16v st1 = (float16v)0.0f;
        __builtin_amdgcn_s_setprio(1);
#pragma unroll
        for (int s = 0; s < 4; s++) {
            bf16x8 ka = *(const bf16x8*)&K_[m * 64 + (((s * 2 + half) ^ (m & 7)) * 8)];
            st0 = __builtin_amdgcn_mfma_f32_32x32x16_bf16(ka, qf[s], st0, 0, 0, 0);
        }
#pragma unroll
        for (int s = 0; s < 4; s++) {
            bf16x8 ka = *(const bf16x8*)&K_[(32 + m) * 64 + (((s * 2 + half) ^ (m & 7)) * 8)];
            st1 = __builtin_amdgcn_mfma_f32_32x32x16_bf16(ka, qf[s], st1, 0, 0, 0);
        }
        __builtin_amdgcn_s_setprio(0);

        // ---- kt=0: softmax (overlaps QK1 in-flight), PV, then tree-sum ----
        {
            float pe[16];
#pragma unroll
            for (int i = 0; i < 16; i++) pe[i] = __builtin_amdgcn_exp2f(st0[i]);
            bf16x8 ap[2];
#pragma unroll
            for (int i = 0; i < 4; i++) {
                ap[0][i]     = (__bf16)pe[i];
                ap[0][4 + i] = (__bf16)pe[8 + i];
                ap[1][i]     = (__bf16)pe[4 + i];
                ap[1][4 + i] = (__bf16)pe[12 + i];
            }
            __builtin_amdgcn_s_setprio(1);
#pragma unroll
            for (int ks = 0; ks < 2; ks++)
#pragma unroll
                for (int dt = 0; dt < 2; dt++) {
                    int row = dt * 32 + m;
                    bf16x8 bv = *(const bf16x8*)&V_[row * 64 + (((ks * 2 + half) ^ (row & 7)) * 8)];
                    accO[dt] = __builtin_amdgcn_mfma_f32_32x32x16_bf16(ap[ks], bv, accO[dt], 0, 0, 0);
                }
            __builtin_amdgcn_s_setprio(0);
            float ps[8];
#pragma unroll
            for (int i = 0; i < 8; i++) ps[i] = pe[i] + pe[i + 8];
#pragma unroll
            for (int i = 0; i < 4; i++) ps[i] += ps[i + 4];
            ps[0] += ps[2]; ps[1] += ps[3];
            lsum += ps[0] + ps[1];
        }

        // ---- kt=1: softmax (overlaps PV0 in-flight), PV, tree-sum ----
        {
            float pe[16];
#pragma unroll
            for (int i = 0; i < 16; i++) pe[i] = __builtin_amdgcn_exp2f(st1[i]);
            bf16x8 ap[2];
#pragma unroll
            for (int i = 0; i < 4; i++) {
                ap[0][i]     = (__bf16)pe[i];
                ap[0][4 + i] = (__bf16)pe[8 + i];
                ap[1][i]     = (__bf16)pe[4 + i];
                ap[1][4 + i] = (__bf16)pe[12 + i];
            }
            __builtin_amdgcn_s_setprio(1);
#pragma unroll
            for (int ks = 0; ks < 2; ks++)
#pragma unroll
                for (int dt = 0; dt < 2; dt++) {
                    int row = dt * 32 + m;
                    bf16x8 bv = *(const bf16x8*)&V_[row * 64 + (((4 + ks * 2 + half) ^ (row & 7)) * 8)];
                    accO[dt] = __builtin_amdgcn_mfma_f32_32x32x16_bf16(ap[ks], bv, accO[dt], 0, 0, 0);
                }
            __builtin_amdgcn_s_setprio(0);
            float ps[8];
#pragma unroll
            for (int i = 0; i < 8; i++) ps[i] = pe[i] + pe[i + 8];
#pragma unroll
            for (int i = 0; i < 4; i++) ps[i] += ps[i + 4];
            ps[0] += ps[2]; ps[1] += ps[3];
            lsum += ps[0] + ps[1];
        }
    }

    {
        float v = lsum + __shfl_xor(lsum, 32);
        float linv = 1.0f / v;
#pragma unroll
        for (int s = 0; s < 4; s++)
#pragma unroll
            for (int i = 0; i < 4; i++) {
                int reg = s * 4 + i;
                int qrow = i + s * 8 + half * 4;
                float ln = __shfl(linv, qrow);
                int qg = q0 + qrow;
                size_t base = (size_t)(b * TT + qg) * DOUT + h * HD + m;
                Ctx[base]      = f2bf(accO[0][reg] * ln);
                Ctx[base + 32] = f2bf(accO[1][reg] * ln);
            }
    }
}

// ---- Out GEMM R20: 128x128 tile, split-K=2 (kz = blockIdx.y & 1), BK=64,
// qkv-identical staging/MFMA economics (32 MFMA/barrier-pair/wave), direct
// atomicAdd epilogue into memset-zeroed out; bias added by kz==0 only. ----
__global__ __launch_bounds__(256) void out_gemm_kernel(const short* __restrict__ Cb,
                                                       const short* __restrict__ Wot,
                                                       const float* __restrict__ bo,
                                                       float* __restrict__ out) {
    __shared__ __align__(16) short ldsA[8192];   // 128 x 64, 16 KB
    __shared__ __align__(16) short ldsB[8192];   // 128 x 64, 16 KB
    const int t = threadIdx.x;
    const int w = t >> 6, lane = t & 63;
    const int quad = lane >> 4, l15 = lane & 15;
    const int m0 = blockIdx.x * 128;
    const int n0 = (blockIdx.y >> 1) * 128;
    const int kz = blockIdx.y & 1;
    const int wm = (w >> 1) * 64, wn = (w & 1) * 64;

    float4v acc[4][4];
    for (int i = 0; i < 4; i++)
        for (int j = 0; j < 4; j++)
            acc[i][j] = (float4v)0.0f;

    const int rA = t >> 3;                               // 0..31
    const int cS = ((t & 7) ^ ((t >> 3) & 7)) * 8;       // source col-granule * 8
    const short* gA0 = Cb + (size_t)(m0 + rA) * DOUT + cS;
    const short* gB0 = Wot + (size_t)(n0 + rA) * DOUT + cS;

    const int kBeg = kz * 384;
    for (int k0 = kBeg; k0 < kBeg + 384; k0 += 64) {
#pragma unroll
        for (int g = 0; g < 4; g++)
            gload_lds16(gA0 + (size_t)g * 32 * DOUT + k0, &ldsA[(g * 256 + t) * 8]);
#pragma unroll
        for (int g = 0; g < 4; g++)
            gload_lds16(gB0 + (size_t)g * 32 * DOUT + k0, &ldsB[(g * 256 + t) * 8]);
        __syncthreads();
#pragma unroll
        for (int kk = 0; kk < 2; kk++) {
            bf16x8 af[4], bfr[4];
            const int pos = ((kk * 4 + quad) ^ (l15 & 7)) * 8;
            for (int i = 0; i < 4; i++) af[i]  = *(const bf16x8*)&ldsA[(wm + i * 16 + l15) * 64 + pos];
            for (int j = 0; j < 4; j++) bfr[j] = *(const bf16x8*)&ldsB[(wn + j * 16 + l15) * 64 + pos];
            for (int i = 0; i < 4; i++)
                for (int j = 0; j < 4; j++)
                    acc[i][j] = __builtin_amdgcn_mfma_f32_16x16x32_bf16(af[i], bfr[j], acc[i][j], 0, 0, 0);
        }
        __syncthreads();
    }

    // Epilogue: atomicAdd into zeroed out; kz==0 contributes the bias.
    for (int j = 0; j < 4; j++) {
        int n = n0 + wn + j * 16 + l15;
        float bias = (kz == 0) ? bo[n] : 0.0f;
        for (int i = 0; i < 4; i++) {
            int mb = m0 + wm + i * 16 + quad * 4;
            for (int r = 0; r < 4; r++)
                atomicAdd(&out[(size_t)(mb + r) * DOUT + n], acc[i][j][r] + bias);
        }
    }
}

extern "C" void kernel_launch(void* const* d_in, const int* in_sizes, int n_in,
                              void* d_out, int out_size, void* d_ws, size_t ws_size,
                              hipStream_t stream) {
    const float* x  = (const float*)d_in[0];
    const float* Wq = (const float*)d_in[1];
    const float* Wk = (const float*)d_in[2];
    const float* Wv = (const float*)d_in[3];
    const float* Wo = (const float*)d_in[4];
    const float* bo = (const float*)d_in[5];
    float* out = (float*)d_out;

    char* ws = (char*)d_ws;
    short* Wqkvt = (short*)(ws + 12582912);   //  3538944
    short* Wot   = (short*)(ws + 16121856);   //  1179648
    short* Qb    = (short*)(ws + 17301504);   // 12582912
    short* Kb    = (short*)(ws + 29884416);   // 12582912
    short* Vt    = (short*)(ws + 42467328);   // 12582912
    short* Cb    = (short*)(ws + 55050240);   // 12582912 -> total 67633152 B

    hipMemsetAsync(out, 0, out_size, stream);
    prep_kernel<<<dim3(24, 24, 4), 256, 0, stream>>>(Wq, Wk, Wv, Wo, Wqkvt, Wot);
    qkv_gemm_kernel<<<dim3(MTOT / 128, NQKV / 128), 256, 0, stream>>>(x, Wqkvt, Qb, Kb, Vt);
    attn_kernel<<<dim3(BB * HH, TT / 128), 256, 0, stream>>>(Qb, Kb, Vt, Cb);
    out_gemm_kernel<<<dim3(MTOT / 128, (DOUT / 128) * 2), 256, 0, stream>>>(Cb, Wot, bo, out);
}

// Round 16
// 200.519 us; speedup vs baseline: 1.1907x; 1.1907x over previous
//
#include <hip/hip_runtime.h>
#include <hip/hip_bf16.h>
#include <stdint.h>

// MHA fwd, B=4 T=2048 D=768 H=12 HD=64, fp32 io, NO mask, scale=1/8.
// R21 = R16/R19 byte-exact (banked best: 198.8/205.6 across two runs).
// R20's split-K atomic out_gemm regressed +33us (atomic RMW + memset +
// 2x Cb reads >> barrier savings). Session verdict: this 2-barrier
// template configuration is the plateau; attn restructures (R7/R10/R11/
// R13), GEMM dbuf (R15), grid swap (R17), T14 prefetch+LB (R18), and
// split-K (R20) all lose for understood, documented reasons.
// Structure: prep (W-transpose) -> qkv (fused fp32-A cast, BK=64, M-fast)
// -> attn (R9 kt-interleave + T5 setprio) -> out (BK=64, M-fast).

#define HH   12
#define TT   2048
#define DIN  768
#define DOUT 768
#define HD   64
#define BB   4
#define MTOT (BB*TT)      // 8192
#define NQKV (3*DOUT)     // 2304
#define QSCALE 0.1803368801111832f   // 0.125 * log2(e)

typedef float  float4v  __attribute__((ext_vector_type(4)));
typedef float  float16v __attribute__((ext_vector_type(16)));
typedef __bf16 bf16x8   __attribute__((ext_vector_type(8)));
typedef short  short8v  __attribute__((ext_vector_type(8)));

#define AS1 __attribute__((address_space(1)))
#define AS3 __attribute__((address_space(3)))

static __device__ __forceinline__ void gload_lds16(const void* g, void* l) {
    __builtin_amdgcn_global_load_lds((AS1 void*)g, (AS3 void*)l, 16, 0, 0);
}

static __device__ __forceinline__ short f2bf(float f) {
    __bf16 h = (__bf16)f;
    return __builtin_bit_cast(short, h);
}

// ---- Prep: weight transpose tiles only (x-cast fused into qkv) ----
__global__ __launch_bounds__(256) void prep_kernel(const float* __restrict__ Wq,
                                                   const float* __restrict__ Wk,
                                                   const float* __restrict__ Wv,
                                                   const float* __restrict__ Wo,
                                                   short* __restrict__ Wqkvt,
                                                   short* __restrict__ Wot) {
    __shared__ short tile[32 * 33];
    const int bz = blockIdx.z;
    const int bx = blockIdx.x, by = blockIdx.y;
    const float* W = (bz == 0) ? Wq : (bz == 1) ? Wk : (bz == 2) ? Wv : Wo;
    const int tx = threadIdx.x & 31, ty = threadIdx.x >> 5;
    for (int i = 0; i < 4; i++) {
        int k = by * 32 + ty + i * 8;
        tile[(ty + i * 8) * 33 + tx] = f2bf(W[(size_t)k * DOUT + bx * 32 + tx]);
    }
    __syncthreads();
    for (int i = 0; i < 4; i++) {
        int n = bx * 32 + ty + i * 8;
        int k = by * 32 + tx;
        short v = tile[tx * 33 + ty + i * 8];
        if (bz < 3) Wqkvt[(size_t)(bz * DOUT + n) * DIN + k] = v;
        else        Wot[(size_t)n * DOUT + k] = v;
    }
}

// ---- QKV GEMM (R16): C[8192][2304] = x(cast) @ Wqkvt^T, BK=64, M-fast.
// A staged from fp32 x via reg-cast (float4 x2 -> cvt -> ds_write_b128),
// producing the EXACT LDS image of the R8/R12 gload path. B via gload_lds.
__global__ __launch_bounds__(256) void qkv_gemm_kernel(const float* __restrict__ x,
                                                       const short* __restrict__ Wt,
                                                       short* __restrict__ Qb,
                                                       short* __restrict__ Kb,
                                                       short* __restrict__ Vt) {
    __shared__ __align__(16) short lds[16384];   // GEMM: A|B 32KB; epilogue: 32KB tile
    short* ldsA = lds;           // 128 x 64
    short* ldsB = lds + 8192;    // 128 x 64
    const int t = threadIdx.x;
    const int w = t >> 6, lane = t & 63;
    const int quad = lane >> 4, l15 = lane & 15;
    const int m0 = blockIdx.x * 128, n0 = blockIdx.y * 128;
    const int wm = (w >> 1) * 64, wn = (w & 1) * 64;

    float4v acc[4][4];
    for (int i = 0; i < 4; i++)
        for (int j = 0; j < 4; j++)
            acc[i][j] = (float4v)0.0f;

    const int rA = t >> 3;                               // 0..31
    const int cS = ((t & 7) ^ ((t >> 3) & 7)) * 8;       // source col-granule * 8
    const float* xA0 = x + (size_t)(m0 + rA) * DIN + cS;
    const short* gB0 = Wt + (size_t)(n0 + rA) * DIN + cS;

    for (int k0 = 0; k0 < DIN; k0 += 64) {
        // B first: fire-and-forget DMA while A reg-stages.
#pragma unroll
        for (int g = 0; g < 4; g++)
            gload_lds16(gB0 + (size_t)g * 32 * DIN + k0, &ldsB[(g * 256 + t) * 8]);
#pragma unroll
        for (int g = 0; g < 4; g++) {
            const float* src = xA0 + (size_t)g * 32 * DIN + k0;
            float4 lo = *(const float4*)src;
            float4 hi = *(const float4*)(src + 4);
            short8v s;
            s[0] = f2bf(lo.x); s[1] = f2bf(lo.y); s[2] = f2bf(lo.z); s[3] = f2bf(lo.w);
            s[4] = f2bf(hi.x); s[5] = f2bf(hi.y); s[6] = f2bf(hi.z); s[7] = f2bf(hi.w);
            *(short8v*)&ldsA[(g * 256 + t) * 8] = s;
        }
        __syncthreads();
#pragma unroll
        for (int kk = 0; kk < 2; kk++) {
            bf16x8 af[4], bfr[4];
            const int pos = ((kk * 4 + quad) ^ (l15 & 7)) * 8;
            for (int i = 0; i < 4; i++) af[i]  = *(const bf16x8*)&ldsA[(wm + i * 16 + l15) * 64 + pos];
            for (int j = 0; j < 4; j++) bfr[j] = *(const bf16x8*)&ldsB[(wn + j * 16 + l15) * 64 + pos];
            for (int i = 0; i < 4; i++)
                for (int j = 0; j < 4; j++)
                    acc[i][j] = __builtin_amdgcn_mfma_f32_16x16x32_bf16(af[i], bfr[j], acc[i][j], 0, 0, 0);
        }
        __syncthreads();
    }

    const int which = n0 / DOUT;
    if (which < 2) {
        // Q/K epilogue: single-pass 128x128 LDS tile, 1 barrier, b128 stores.
        short* ldsT = lds;   // 128 x 128 shorts = 32 KB
        const float sc = (which == 0) ? QSCALE : 1.0f;
        short* dst = (which == 0) ? Qb : Kb;
        const int n0sec = n0 - which * DOUT;
        for (int i = 0; i < 4; i++)
            for (int j = 0; j < 4; j++) {
                int col = wn + j * 16 + l15;
                int cx = col >> 3, co = col & 7;
                for (int r = 0; r < 4; r++) {
                    int row = wm + i * 16 + quad * 4 + r;
                    ldsT[row * 128 + ((cx ^ (row & 7)) * 8 + co)] = f2bf(acc[i][j][r] * sc);
                }
            }
        __syncthreads();
        for (int p = 0; p < 8; p++) {
            int row = p * 16 + (t >> 4);
            int cL = t & 15;
            short8v v = *(const short8v*)&ldsT[row * 128 + ((cL ^ (row & 7)) * 8)];
            int mg = m0 + row;
            int b2 = mg >> 11, tq = mg & 2047;
            int colg = n0sec + cL * 8;
            int hh = colg >> 6, d = colg & 63;
            *(short8v*)&dst[((size_t)((b2 * HH + hh) * TT + tq) << 6) + d] = v;
        }
    } else {
        // V epilogue: single-pass transpose 128(d) x 128(t) LDS tile, b128 stores.
        short* ldsT = lds;   // 128 x 128 shorts = 32 KB
        const int n0r = n0 - 2 * DOUT;
        const int b = m0 >> 11, tq0 = m0 & 2047;
        for (int i = 0; i < 4; i++)
            for (int j = 0; j < 4; j++)
                for (int r = 0; r < 4; r++) {
                    int nl = wn + j * 16 + l15;            // d-direction 0..127
                    int ml = wm + i * 16 + quad * 4 + r;   // t-direction 0..127
                    int c = ml >> 3, o = ml & 7;
                    ldsT[nl * 128 + ((c ^ (nl & 7)) * 8 + o)] = f2bf(acc[i][j][r]);
                }
        __syncthreads();
        for (int p = 0; p < 8; p++) {
            int nrow = p * 16 + (t >> 4);
            int cc = t & 15;
            short8v v = *(const short8v*)&ldsT[nrow * 128 + ((cc ^ (nrow & 7)) * 8)];
            int colg = n0r + nrow;
            int hh = colg >> 6, d = colg & 63;
            *(short8v*)&Vt[(size_t)((b * HH + hh) * HD + d) * TT + tq0 + cc * 8] = v;
        }
    }
}

// ---- Flash attention (R12/R9, banked): kt-interleave + T5 setprio ----
__global__ __launch_bounds__(256, 3) void attn_kernel(const short* __restrict__ Qb,
                                                      const short* __restrict__ Kb,
                                                      const short* __restrict__ Vt,
                                                      short* __restrict__ Ctx) {
    __shared__ __align__(16) short ldsK[2][64 * 64];
    __shared__ __align__(16) short ldsV[2][64 * 64];
    const int t = threadIdx.x;
    const int w = t >> 6, lane = t & 63;
    const int half = lane >> 5, m = lane & 31;
    const int bh = blockIdx.x;
    const int b = bh / HH, h = bh - b * HH;
    const int q0 = blockIdx.y * 128 + w * 32;

    const short* Qbase = Qb + (size_t)bh * TT * HD;
    const short* Kbase = Kb + (size_t)bh * TT * HD;
    const short* Vbase = Vt + (size_t)bh * HD * TT;

    bf16x8 qf[4];
#pragma unroll
    for (int s = 0; s < 4; s++)
        qf[s] = *(const bf16x8*)&Qbase[(q0 + m) * HD + s * 16 + half * 8];

    int kOff[2], vOff[2];
    {
        int r5 = t >> 3;
        int pi = ((r5 >> 3) & 1) * 16 + ((r5 >> 2) & 1) * 8 + ((r5 >> 4) & 1) * 4 + (r5 & 3);
#pragma unroll
        for (int g = 0; g < 2; g++) {
            kOff[g] = (g * 32 + pi) * 64 + (((t & 7) ^ (r5 & 7)) * 8);
            int vrow = g * 32 + r5;
            vOff[g] = vrow * TT + (((t & 7) ^ (vrow & 7)) * 8);
        }
    }

    auto stage = [&](int buf, int u0) {
#pragma unroll
        for (int g = 0; g < 2; g++)
            gload_lds16(Kbase + (size_t)u0 * 64 + kOff[g], &ldsK[buf][(g * 256 + t) * 8]);
#pragma unroll
        for (int g = 0; g < 2; g++)
            gload_lds16(Vbase + (size_t)u0 + vOff[g], &ldsV[buf][(g * 256 + t) * 8]);
    };

    float16v accO[2];
    accO[0] = (float16v)0.0f;
    accO[1] = (float16v)0.0f;
    float lsum = 0.0f;

    stage(0, 0);

    for (int it = 0; it < TT / 64; ++it) {
        __syncthreads();
        const int buf = it & 1;
        if (it + 1 < TT / 64) stage(buf ^ 1, (it + 1) * 64);
        const short* K_ = &ldsK[buf][0];
        const short* V_ = &ldsV[buf][0];

        // ---- QK for both kt halves: two independent accumulation chains ----
        float16v st0 = (float16v)0.0f;
        float16v st1 = (float16v)0.0f;
        __builtin_amdgcn_s_setprio(1);
#pragma unroll
        for (int s = 0; s < 4; s++) {
            bf16x8 ka = *(const bf16x8*)&K_[m * 64 + (((s * 2 + half) ^ (m & 7)) * 8)];
            st0 = __builtin_amdgcn_mfma_f32_32x32x16_bf16(ka, qf[s], st0, 0, 0, 0);
        }
#pragma unroll
        for (int s = 0; s < 4; s++) {
            bf16x8 ka = *(const bf16x8*)&K_[(32 + m) * 64 + (((s * 2 + half) ^ (m & 7)) * 8)];
            st1 = __builtin_amdgcn_mfma_f32_32x32x16_bf16(ka, qf[s], st1, 0, 0, 0);
        }
        __builtin_amdgcn_s_setprio(0);

        // ---- kt=0: softmax (overlaps QK1 in-flight), PV, then tree-sum ----
        {
            float pe[16];
#pragma unroll
            for (int i = 0; i < 16; i++) pe[i] = __builtin_amdgcn_exp2f(st0[i]);
            bf16x8 ap[2];
#pragma unroll
            for (int i = 0; i < 4; i++) {
                ap[0][i]     = (__bf16)pe[i];
                ap[0][4 + i] = (__bf16)pe[8 + i];
                ap[1][i]     = (__bf16)pe[4 + i];
                ap[1][4 + i] = (__bf16)pe[12 + i];
            }
            __builtin_amdgcn_s_setprio(1);
#pragma unroll
            for (int ks = 0; ks < 2; ks++)
#pragma unroll
                for (int dt = 0; dt < 2; dt++) {
                    int row = dt * 32 + m;
                    bf16x8 bv = *(const bf16x8*)&V_[row * 64 + (((ks * 2 + half) ^ (row & 7)) * 8)];
                    accO[dt] = __builtin_amdgcn_mfma_f32_32x32x16_bf16(ap[ks], bv, accO[dt], 0, 0, 0);
                }
            __builtin_amdgcn_s_setprio(0);
            float ps[8];
#pragma unroll
            for (int i = 0; i < 8; i++) ps[i] = pe[i] + pe[i + 8];
#pragma unroll
            for (int i = 0; i < 4; i++) ps[i] += ps[i + 4];
            ps[0] += ps[2]; ps[1] += ps[3];
            lsum += ps[0] + ps[1];
        }

        // ---- kt=1: softmax (overlaps PV0 in-flight), PV, tree-sum ----
        {
            float pe[16];
#pragma unroll
            for (int i = 0; i < 16; i++) pe[i] = __builtin_amdgcn_exp2f(st1[i]);
            bf16x8 ap[2];
#pragma unroll
            for (int i = 0; i < 4; i++) {
                ap[0][i]     = (__bf16)pe[i];
                ap[0][4 + i] = (__bf16)pe[8 + i];
                ap[1][i]     = (__bf16)pe[4 + i];
                ap[1][4 + i] = (__bf16)pe[12 + i];
            }
            __builtin_amdgcn_s_setprio(1);
#pragma unroll
            for (int ks = 0; ks < 2; ks++)
#pragma unroll
                for (int dt = 0; dt < 2; dt++) {
                    int row = dt * 32 + m;
                    bf16x8 bv = *(const bf16x8*)&V_[row * 64 + (((4 + ks * 2 + half) ^ (row & 7)) * 8)];
                    accO[dt] = __builtin_amdgcn_mfma_f32_32x32x16_bf16(ap[ks], bv, accO[dt], 0, 0, 0);
                }
            __builtin_amdgcn_s_setprio(0);
            float ps[8];
#pragma unroll
            for (int i = 0; i < 8; i++) ps[i] = pe[i] + pe[i + 8];
#pragma unroll
            for (int i = 0; i < 4; i++) ps[i] += ps[i + 4];
            ps[0] += ps[2]; ps[1] += ps[3];
            lsum += ps[0] + ps[1];
        }
    }

    {
        float v = lsum + __shfl_xor(lsum, 32);
        float linv = 1.0f / v;
#pragma unroll
        for (int s = 0; s < 4; s++)
#pragma unroll
            for (int i = 0; i < 4; i++) {
                int reg = s * 4 + i;
                int qrow = i + s * 8 + half * 4;
                float ln = __shfl(linv, qrow);
                int qg = q0 + qrow;
                size_t base = (size_t)(b * TT + qg) * DOUT + h * HD + m;
                Ctx[base]      = f2bf(accO[0][reg] * ln);
                Ctx[base + 32] = f2bf(accO[1][reg] * ln);
            }
    }
}

// ---- Out GEMM (R16/R12): M-fast grid, 64x128 tiles, BK=64 ----
__global__ __launch_bounds__(256) void out_gemm_kernel(const short* __restrict__ Cb,
                                                       const short* __restrict__ Wot,
                                                       const float* __restrict__ bo,
                                                       float* __restrict__ out) {
    __shared__ __align__(16) short ldsA[64 * 64];    //  8 KB
    __shared__ __align__(16) short ldsB[128 * 64];   // 16 KB
    const int t = threadIdx.x;
    const int w = t >> 6, lane = t & 63;
    const int quad = lane >> 4, l15 = lane & 15;
    const int m0 = blockIdx.x * 64, n0 = blockIdx.y * 128;
    const int wn = w * 32;

    float4v acc[4][2];
    for (int i = 0; i < 4; i++)
        for (int j = 0; j < 2; j++)
            acc[i][j] = (float4v)0.0f;

    const int rA = t >> 3;                               // 0..31
    const int cS = ((t & 7) ^ ((t >> 3) & 7)) * 8;       // source col-granule * 8
    const short* gA0 = Cb + (size_t)(m0 + rA) * DOUT + cS;
    const short* gB0 = Wot + (size_t)(n0 + rA) * DOUT + cS;

    for (int k0 = 0; k0 < DOUT; k0 += 64) {
#pragma unroll
        for (int g = 0; g < 2; g++)
            gload_lds16(gA0 + (size_t)g * 32 * DOUT + k0, &ldsA[(g * 256 + t) * 8]);
#pragma unroll
        for (int g = 0; g < 4; g++)
            gload_lds16(gB0 + (size_t)g * 32 * DOUT + k0, &ldsB[(g * 256 + t) * 8]);
        __syncthreads();
#pragma unroll
        for (int kk = 0; kk < 2; kk++) {
            bf16x8 af[4], bfr[2];
            const int pos = ((kk * 4 + quad) ^ (l15 & 7)) * 8;
            for (int i = 0; i < 4; i++) af[i]  = *(const bf16x8*)&ldsA[(i * 16 + l15) * 64 + pos];
            for (int j = 0; j < 2; j++) bfr[j] = *(const bf16x8*)&ldsB[(wn + j * 16 + l15) * 64 + pos];
            for (int i = 0; i < 4; i++)
                for (int j = 0; j < 2; j++)
                    acc[i][j] = __builtin_amdgcn_mfma_f32_16x16x32_bf16(af[i], bfr[j], acc[i][j], 0, 0, 0);
        }
        __syncthreads();
    }

    for (int i = 0; i < 4; i++) {
        int m = m0 + i * 16 + quad * 4;
        for (int j = 0; j < 2; j++) {
            int n = n0 + wn + j * 16 + l15;
            float bias = bo[n];
            for (int r = 0; r < 4; r++)
                out[(size_t)(m + r) * DOUT + n] = acc[i][j][r] + bias;
        }
    }
}

extern "C" void kernel_launch(void* const* d_in, const int* in_sizes, int n_in,
                              void* d_out, int out_size, void* d_ws, size_t ws_size,
                              hipStream_t stream) {
    const float* x  = (const float*)d_in[0];
    const float* Wq = (const float*)d_in[1];
    const float* Wk = (const float*)d_in[2];
    const float* Wv = (const float*)d_in[3];
    const float* Wo = (const float*)d_in[4];
    const float* bo = (const float*)d_in[5];
    float* out = (float*)d_out;

    char* ws = (char*)d_ws;
    short* Wqkvt = (short*)(ws + 12582912);   //  3538944
    short* Wot   = (short*)(ws + 16121856);   //  1179648
    short* Qb    = (short*)(ws + 17301504);   // 12582912
    short* Kb    = (short*)(ws + 29884416);   // 12582912
    short* Vt    = (short*)(ws + 42467328);   // 12582912
    short* Cb    = (short*)(ws + 55050240);   // 12582912 -> total 67633152 B

    prep_kernel<<<dim3(24, 24, 4), 256, 0, stream>>>(Wq, Wk, Wv, Wo, Wqkvt, Wot);
    qkv_gemm_kernel<<<dim3(MTOT / 128, NQKV / 128), 256, 0, stream>>>(x, Wqkvt, Qb, Kb, Vt);
    attn_kernel<<<dim3(BB * HH, TT / 128), 256, 0, stream>>>(Qb, Kb, Vt, Cb);
    out_gemm_kernel<<<dim3(MTOT / 64, DOUT / 128), 256, 0, stream>>>(Cb, Wot, bo, out);
}

// Round 17
// 200.255 us; speedup vs baseline: 1.1922x; 1.0013x over previous
//
#include <hip/hip_runtime.h>
#include <hip/hip_bf16.h>
#include <stdint.h>

// MHA fwd, B=4 T=2048 D=768 H=12 HD=64, fp32 io, NO mask, scale=1/8.
// FINAL (R16/R19/R21, measured 198.8/205.6/200.5): structural plateau of
// the 2-barrier template family. Eight structural experiments regressed or
// nulled with understood mechanisms (see session journal R7-R20). Wins
// banked: T5 setprio + kt-interleave attn, BK=64 GEMMs, fused x-cast,
// fused prep. Path beyond: 8-phase T2-T5 co-designed stack (rewrite).
// Structure: prep (W-transpose) -> qkv (fused fp32-A cast, BK=64, M-fast)
// -> attn (R9 kt-interleave + T5 setprio) -> out (BK=64, M-fast).

#define HH   12
#define TT   2048
#define DIN  768
#define DOUT 768
#define HD   64
#define BB   4
#define MTOT (BB*TT)      // 8192
#define NQKV (3*DOUT)     // 2304
#define QSCALE 0.1803368801111832f   // 0.125 * log2(e)

typedef float  float4v  __attribute__((ext_vector_type(4)));
typedef float  float16v __attribute__((ext_vector_type(16)));
typedef __bf16 bf16x8   __attribute__((ext_vector_type(8)));
typedef short  short8v  __attribute__((ext_vector_type(8)));

#define AS1 __attribute__((address_space(1)))
#define AS3 __attribute__((address_space(3)))

static __device__ __forceinline__ void gload_lds16(const void* g, void* l) {
    __builtin_amdgcn_global_load_lds((AS1 void*)g, (AS3 void*)l, 16, 0, 0);
}

static __device__ __forceinline__ short f2bf(float f) {
    __bf16 h = (__bf16)f;
    return __builtin_bit_cast(short, h);
}

// ---- Prep: weight transpose tiles only (x-cast fused into qkv) ----
__global__ __launch_bounds__(256) void prep_kernel(const float* __restrict__ Wq,
                                                   const float* __restrict__ Wk,
                                                   const float* __restrict__ Wv,
                                                   const float* __restrict__ Wo,
                                                   short* __restrict__ Wqkvt,
                                                   short* __restrict__ Wot) {
    __shared__ short tile[32 * 33];
    const int bz = blockIdx.z;
    const int bx = blockIdx.x, by = blockIdx.y;
    const float* W = (bz == 0) ? Wq : (bz == 1) ? Wk : (bz == 2) ? Wv : Wo;
    const int tx = threadIdx.x & 31, ty = threadIdx.x >> 5;
    for (int i = 0; i < 4; i++) {
        int k = by * 32 + ty + i * 8;
        tile[(ty + i * 8) * 33 + tx] = f2bf(W[(size_t)k * DOUT + bx * 32 + tx]);
    }
    __syncthreads();
    for (int i = 0; i < 4; i++) {
        int n = bx * 32 + ty + i * 8;
        int k = by * 32 + tx;
        short v = tile[tx * 33 + ty + i * 8];
        if (bz < 3) Wqkvt[(size_t)(bz * DOUT + n) * DIN + k] = v;
        else        Wot[(size_t)n * DOUT + k] = v;
    }
}

// ---- QKV GEMM: C[8192][2304] = x(cast) @ Wqkvt^T, BK=64, M-fast.
// A staged from fp32 x via reg-cast (float4 x2 -> cvt -> ds_write_b128);
// B via gload_lds (fire-and-forget DMA issued first).
__global__ __launch_bounds__(256) void qkv_gemm_kernel(const float* __restrict__ x,
                                                       const short* __restrict__ Wt,
                                                       short* __restrict__ Qb,
                                                       short* __restrict__ Kb,
                                                       short* __restrict__ Vt) {
    __shared__ __align__(16) short lds[16384];   // GEMM: A|B 32KB; epilogue: 32KB tile
    short* ldsA = lds;           // 128 x 64
    short* ldsB = lds + 8192;    // 128 x 64
    const int t = threadIdx.x;
    const int w = t >> 6, lane = t & 63;
    const int quad = lane >> 4, l15 = lane & 15;
    const int m0 = blockIdx.x * 128, n0 = blockIdx.y * 128;
    const int wm = (w >> 1) * 64, wn = (w & 1) * 64;

    float4v acc[4][4];
    for (int i = 0; i < 4; i++)
        for (int j = 0; j < 4; j++)
            acc[i][j] = (float4v)0.0f;

    const int rA = t >> 3;                               // 0..31
    const int cS = ((t & 7) ^ ((t >> 3) & 7)) * 8;       // source col-granule * 8
    const float* xA0 = x + (size_t)(m0 + rA) * DIN + cS;
    const short* gB0 = Wt + (size_t)(n0 + rA) * DIN + cS;

    for (int k0 = 0; k0 < DIN; k0 += 64) {
#pragma unroll
        for (int g = 0; g < 4; g++)
            gload_lds16(gB0 + (size_t)g * 32 * DIN + k0, &ldsB[(g * 256 + t) * 8]);
#pragma unroll
        for (int g = 0; g < 4; g++) {
            const float* src = xA0 + (size_t)g * 32 * DIN + k0;
            float4 lo = *(const float4*)src;
            float4 hi = *(const float4*)(src + 4);
            short8v s;
            s[0] = f2bf(lo.x); s[1] = f2bf(lo.y); s[2] = f2bf(lo.z); s[3] = f2bf(lo.w);
            s[4] = f2bf(hi.x); s[5] = f2bf(hi.y); s[6] = f2bf(hi.z); s[7] = f2bf(hi.w);
            *(short8v*)&ldsA[(g * 256 + t) * 8] = s;
        }
        __syncthreads();
#pragma unroll
        for (int kk = 0; kk < 2; kk++) {
            bf16x8 af[4], bfr[4];
            const int pos = ((kk * 4 + quad) ^ (l15 & 7)) * 8;
            for (int i = 0; i < 4; i++) af[i]  = *(const bf16x8*)&ldsA[(wm + i * 16 + l15) * 64 + pos];
            for (int j = 0; j < 4; j++) bfr[j] = *(const bf16x8*)&ldsB[(wn + j * 16 + l15) * 64 + pos];
            for (int i = 0; i < 4; i++)
                for (int j = 0; j < 4; j++)
                    acc[i][j] = __builtin_amdgcn_mfma_f32_16x16x32_bf16(af[i], bfr[j], acc[i][j], 0, 0, 0);
        }
        __syncthreads();
    }

    const int which = n0 / DOUT;
    if (which < 2) {
        // Q/K epilogue: single-pass 128x128 LDS tile, 1 barrier, b128 stores.
        short* ldsT = lds;   // 128 x 128 shorts = 32 KB
        const float sc = (which == 0) ? QSCALE : 1.0f;
        short* dst = (which == 0) ? Qb : Kb;
        const int n0sec = n0 - which * DOUT;
        for (int i = 0; i < 4; i++)
            for (int j = 0; j < 4; j++) {
                int col = wn + j * 16 + l15;
                int cx = col >> 3, co = col & 7;
                for (int r = 0; r < 4; r++) {
                    int row = wm + i * 16 + quad * 4 + r;
                    ldsT[row * 128 + ((cx ^ (row & 7)) * 8 + co)] = f2bf(acc[i][j][r] * sc);
                }
            }
        __syncthreads();
        for (int p = 0; p < 8; p++) {
            int row = p * 16 + (t >> 4);
            int cL = t & 15;
            short8v v = *(const short8v*)&ldsT[row * 128 + ((cL ^ (row & 7)) * 8)];
            int mg = m0 + row;
            int b2 = mg >> 11, tq = mg & 2047;
            int colg = n0sec + cL * 8;
            int hh = colg >> 6, d = colg & 63;
            *(short8v*)&dst[((size_t)((b2 * HH + hh) * TT + tq) << 6) + d] = v;
        }
    } else {
        // V epilogue: single-pass transpose 128(d) x 128(t) LDS tile, b128 stores.
        short* ldsT = lds;   // 128 x 128 shorts = 32 KB
        const int n0r = n0 - 2 * DOUT;
        const int b = m0 >> 11, tq0 = m0 & 2047;
        for (int i = 0; i < 4; i++)
            for (int j = 0; j < 4; j++)
                for (int r = 0; r < 4; r++) {
                    int nl = wn + j * 16 + l15;            // d-direction 0..127
                    int ml = wm + i * 16 + quad * 4 + r;   // t-direction 0..127
                    int c = ml >> 3, o = ml & 7;
                    ldsT[nl * 128 + ((c ^ (nl & 7)) * 8 + o)] = f2bf(acc[i][j][r]);
                }
        __syncthreads();
        for (int p = 0; p < 8; p++) {
            int nrow = p * 16 + (t >> 4);
            int cc = t & 15;
            short8v v = *(const short8v*)&ldsT[nrow * 128 + ((cc ^ (nrow & 7)) * 8)];
            int colg = n0r + nrow;
            int hh = colg >> 6, d = colg & 63;
            *(short8v*)&Vt[(size_t)((b * HH + hh) * HD + d) * TT + tq0 + cc * 8] = v;
        }
    }
}

// ---- Flash attention: kt-interleave + T5 setprio, 4 waves x 32q, 3 blk/CU ----
__global__ __launch_bounds__(256, 3) void attn_kernel(const short* __restrict__ Qb,
                                                      const short* __restrict__ Kb,
                                                      const short* __restrict__ Vt,
                                                      short* __restrict__ Ctx) {
    __shared__ __align__(16) short ldsK[2][64 * 64];
    __shared__ __align__(16) short ldsV[2][64 * 64];
    const int t = threadIdx.x;
    const int w = t >> 6, lane = t & 63;
    const int half = lane >> 5, m = lane & 31;
    const int bh = blockIdx.x;
    const int b = bh / HH, h = bh - b * HH;
    const int q0 = blockIdx.y * 128 + w * 32;

    const short* Qbase = Qb + (size_t)bh * TT * HD;
    const short* Kbase = Kb + (size_t)bh * TT * HD;
    const short* Vbase = Vt + (size_t)bh * HD * TT;

    bf16x8 qf[4];
#pragma unroll
    for (int s = 0; s < 4; s++)
        qf[s] = *(const bf16x8*)&Qbase[(q0 + m) * HD + s * 16 + half * 8];

    int kOff[2], vOff[2];
    {
        int r5 = t >> 3;
        int pi = ((r5 >> 3) & 1) * 16 + ((r5 >> 2) & 1) * 8 + ((r5 >> 4) & 1) * 4 + (r5 & 3);
#pragma unroll
        for (int g = 0; g < 2; g++) {
            kOff[g] = (g * 32 + pi) * 64 + (((t & 7) ^ (r5 & 7)) * 8);
            int vrow = g * 32 + r5;
            vOff[g] = vrow * TT + (((t & 7) ^ (vrow & 7)) * 8);
        }
    }

    auto stage = [&](int buf, int u0) {
#pragma unroll
        for (int g = 0; g < 2; g++)
            gload_lds16(Kbase + (size_t)u0 * 64 + kOff[g], &ldsK[buf][(g * 256 + t) * 8]);
#pragma unroll
        for (int g = 0; g < 2; g++)
            gload_lds16(Vbase + (size_t)u0 + vOff[g], &ldsV[buf][(g * 256 + t) * 8]);
    };

    float16v accO[2];
    accO[0] = (float16v)0.0f;
    accO[1] = (float16v)0.0f;
    float lsum = 0.0f;

    stage(0, 0);

    for (int it = 0; it < TT / 64; ++it) {
        __syncthreads();
        const int buf = it & 1;
        if (it + 1 < TT / 64) stage(buf ^ 1, (it + 1) * 64);
        const short* K_ = &ldsK[buf][0];
        const short* V_ = &ldsV[buf][0];

        // ---- QK for both kt halves: two independent accumulation chains ----
        float16v st0 = (float16v)0.0f;
        float16v st1 = (float16v)0.0f;
        __builtin_amdgcn_s_setprio(1);
#pragma unroll
        for (int s = 0; s < 4; s++) {
            bf16x8 ka = *(const bf16x8*)&K_[m * 64 + (((s * 2 + half) ^ (m & 7)) * 8)];
            st0 = __builtin_amdgcn_mfma_f32_32x32x16_bf16(ka, qf[s], st0, 0, 0, 0);
        }
#pragma unroll
        for (int s = 0; s < 4; s++) {
            bf16x8 ka = *(const bf16x8*)&K_[(32 + m) * 64 + (((s * 2 + half) ^ (m & 7)) * 8)];
            st1 = __builtin_amdgcn_mfma_f32_32x32x16_bf16(ka, qf[s], st1, 0, 0, 0);
        }
        __builtin_amdgcn_s_setprio(0);

        // ---- kt=0: softmax (overlaps QK1 in-flight), PV, then tree-sum ----
        {
            float pe[16];
#pragma unroll
            for (int i = 0; i < 16; i++) pe[i] = __builtin_amdgcn_exp2f(st0[i]);
            bf16x8 ap[2];
#pragma unroll
            for (int i = 0; i < 4; i++) {
                ap[0][i]     = (__bf16)pe[i];
                ap[0][4 + i] = (__bf16)pe[8 + i];
                ap[1][i]     = (__bf16)pe[4 + i];
                ap[1][4 + i] = (__bf16)pe[12 + i];
            }
            __builtin_amdgcn_s_setprio(1);
#pragma unroll
            for (int ks = 0; ks < 2; ks++)
#pragma unroll
                for (int dt = 0; dt < 2; dt++) {
                    int row = dt * 32 + m;
                    bf16x8 bv = *(const bf16x8*)&V_[row * 64 + (((ks * 2 + half) ^ (row & 7)) * 8)];
                    accO[dt] = __builtin_amdgcn_mfma_f32_32x32x16_bf16(ap[ks], bv, accO[dt], 0, 0, 0);
                }
            __builtin_amdgcn_s_setprio(0);
            float ps[8];
#pragma unroll
            for (int i = 0; i < 8; i++) ps[i] = pe[i] + pe[i + 8];
#pragma unroll
            for (int i = 0; i < 4; i++) ps[i] += ps[i + 4];
            ps[0] += ps[2]; ps[1] += ps[3];
            lsum += ps[0] + ps[1];
        }

        // ---- kt=1: softmax (overlaps PV0 in-flight), PV, tree-sum ----
        {
            float pe[16];
#pragma unroll
            for (int i = 0; i < 16; i++) pe[i] = __builtin_amdgcn_exp2f(st1[i]);
            bf16x8 ap[2];
#pragma unroll
            for (int i = 0; i < 4; i++) {
                ap[0][i]     = (__bf16)pe[i];
                ap[0][4 + i] = (__bf16)pe[8 + i];
                ap[1][i]     = (__bf16)pe[4 + i];
                ap[1][4 + i] = (__bf16)pe[12 + i];
            }
            __builtin_amdgcn_s_setprio(1);
#pragma unroll
            for (int ks = 0; ks < 2; ks++)
#pragma unroll
                for (int dt = 0; dt < 2; dt++) {
                    int row = dt * 32 + m;
                    bf16x8 bv = *(const bf16x8*)&V_[row * 64 + (((4 + ks * 2 + half) ^ (row & 7)) * 8)];
                    accO[dt] = __builtin_amdgcn_mfma_f32_32x32x16_bf16(ap[ks], bv, accO[dt], 0, 0, 0);
                }
            __builtin_amdgcn_s_setprio(0);
            float ps[8];
#pragma unroll
            for (int i = 0; i < 8; i++) ps[i] = pe[i] + pe[i + 8];
#pragma unroll
            for (int i = 0; i < 4; i++) ps[i] += ps[i + 4];
            ps[0] += ps[2]; ps[1] += ps[3];
            lsum += ps[0] + ps[1];
        }
    }

    {
        float v = lsum + __shfl_xor(lsum, 32);
        float linv = 1.0f / v;
#pragma unroll
        for (int s = 0; s < 4; s++)
#pragma unroll
            for (int i = 0; i < 4; i++) {
                int reg = s * 4 + i;
                int qrow = i + s * 8 + half * 4;
                float ln = __shfl(linv, qrow);
                int qg = q0 + qrow;
                size_t base = (size_t)(b * TT + qg) * DOUT + h * HD + m;
                Ctx[base]      = f2bf(accO[0][reg] * ln);
                Ctx[base + 32] = f2bf(accO[1][reg] * ln);
            }
    }
}

// ---- Out GEMM: M-fast grid, 64x128 tiles, BK=64, 768 blocks = 3/CU ----
__global__ __launch_bounds__(256) void out_gemm_kernel(const short* __restrict__ Cb,
                                                       const short* __restrict__ Wot,
                                                       const float* __restrict__ bo,
                                                       float* __restrict__ out) {
    __shared__ __align__(16) short ldsA[64 * 64];    //  8 KB
    __shared__ __align__(16) short ldsB[128 * 64];   // 16 KB
    const int t = threadIdx.x;
    const int w = t >> 6, lane = t & 63;
    const int quad = lane >> 4, l15 = lane & 15;
    const int m0 = blockIdx.x * 64, n0 = blockIdx.y * 128;
    const int wn = w * 32;

    float4v acc[4][2];
    for (int i = 0; i < 4; i++)
        for (int j = 0; j < 2; j++)
            acc[i][j] = (float4v)0.0f;

    const int rA = t >> 3;                               // 0..31
    const int cS = ((t & 7) ^ ((t >> 3) & 7)) * 8;       // source col-granule * 8
    const short* gA0 = Cb + (size_t)(m0 + rA) * DOUT + cS;
    const short* gB0 = Wot + (size_t)(n0 + rA) * DOUT + cS;

    for (int k0 = 0; k0 < DOUT; k0 += 64) {
#pragma unroll
        for (int g = 0; g < 2; g++)
            gload_lds16(gA0 + (size_t)g * 32 * DOUT + k0, &ldsA[(g * 256 + t) * 8]);
#pragma unroll
        for (int g = 0; g < 4; g++)
            gload_lds16(gB0 + (size_t)g * 32 * DOUT + k0, &ldsB[(g * 256 + t) * 8]);
        __syncthreads();
#pragma unroll
        for (int kk = 0; kk < 2; kk++) {
            bf16x8 af[4], bfr[2];
            const int pos = ((kk * 4 + quad) ^ (l15 & 7)) * 8;
            for (int i = 0; i < 4; i++) af[i]  = *(const bf16x8*)&ldsA[(i * 16 + l15) * 64 + pos];
            for (int j = 0; j < 2; j++) bfr[j] = *(const bf16x8*)&ldsB[(wn + j * 16 + l15) * 64 + pos];
            for (int i = 0; i < 4; i++)
                for (int j = 0; j < 2; j++)
                    acc[i][j] = __builtin_amdgcn_mfma_f32_16x16x32_bf16(af[i], bfr[j], acc[i][j], 0, 0, 0);
        }
        __syncthreads();
    }

    for (int i = 0; i < 4; i++) {
        int m = m0 + i * 16 + quad * 4;
        for (int j = 0; j < 2; j++) {
            int n = n0 + wn + j * 16 + l15;
            float bias = bo[n];
            for (int r = 0; r < 4; r++)
                out[(size_t)(m + r) * DOUT + n] = acc[i][j][r] + bias;
        }
    }
}

extern "C" void kernel_launch(void* const* d_in, const int* in_sizes, int n_in,
                              void* d_out, int out_size, void* d_ws, size_t ws_size,
                              hipStream_t stream) {
    const float* x  = (const float*)d_in[0];
    const float* Wq = (const float*)d_in[1];
    const float* Wk = (const float*)d_in[2];
    const float* Wv = (const float*)d_in[3];
    const float* Wo = (const float*)d_in[4];
    const float* bo = (const float*)d_in[5];
    float* out = (float*)d_out;

    char* ws = (char*)d_ws;
    short* Wqkvt = (short*)(ws + 12582912);   //  3538944
    short* Wot   = (short*)(ws + 16121856);   //  1179648
    short* Qb    = (short*)(ws + 17301504);   // 12582912
    short* Kb    = (short*)(ws + 29884416);   // 12582912
    short* Vt    = (short*)(ws + 42467328);   // 12582912
    short* Cb    = (short*)(ws + 55050240);   // 12582912 -> total 67633152 B

    prep_kernel<<<dim3(24, 24, 4), 256, 0, stream>>>(Wq, Wk, Wv, Wo, Wqkvt, Wot);
    qkv_gemm_kernel<<<dim3(MTOT / 128, NQKV / 128), 256, 0, stream>>>(x, Wqkvt, Qb, Kb, Vt);
    attn_kernel<<<dim3(BB * HH, TT / 128), 256, 0, stream>>>(Qb, Kb, Vt, Cb);
    out_gemm_kernel<<<dim3(MTOT / 64, DOUT / 128), 256, 0, stream>>>(Cb, Wot, bo, out);
}